// Round 12
// baseline (339.783 us; speedup 1.0000x reference)
//
#include <hip/hip_runtime.h>
#include <hip/hip_bf16.h>
#include <cstdint>
#include <cstddef>

#define NEG_SLOPE 0.2f

static constexpr int Gg = 2;
static constexpr int Nn = 20000;
static constexpr int Ee = 160000;
static constexpr int Ff = 128;
static constexpr int Cc = 64;
static constexpr int HC = 512;
static constexpr int GN = Gg * Nn;
static constexpr int GNP = 40064;  // GN padded to 128 multiple
static constexpr int DEGMAX = 48;  // padded CSR stride; P(deg>48) ~ 1e-20 (Poisson mean 8)

typedef __attribute__((ext_vector_type(8))) short short8;
typedef __attribute__((ext_vector_type(4))) float floatx4;

// ---------- helpers ----------
__device__ __forceinline__ float bf2f(unsigned short b) {
    return __uint_as_float(((unsigned)b) << 16);
}
__device__ __forceinline__ unsigned short f2bf(float x) {
    unsigned u = __float_as_uint(x);
    unsigned r = 0x7fffu + ((u >> 16) & 1u);
    return (unsigned short)((u + r) >> 16);
}
__device__ __forceinline__ void unpack8(const uint4 p, float* f) {
    f[0] = __uint_as_float(p.x << 16); f[1] = __uint_as_float(p.x & 0xffff0000u);
    f[2] = __uint_as_float(p.y << 16); f[3] = __uint_as_float(p.y & 0xffff0000u);
    f[4] = __uint_as_float(p.z << 16); f[5] = __uint_as_float(p.z & 0xffff0000u);
    f[6] = __uint_as_float(p.w << 16); f[7] = __uint_as_float(p.w & 0xffff0000u);
}
__device__ __forceinline__ void unpack4(const uint2 p, float* f) {
    f[0] = __uint_as_float(p.x << 16); f[1] = __uint_as_float(p.x & 0xffff0000u);
    f[2] = __uint_as_float(p.y << 16); f[3] = __uint_as_float(p.y & 0xffff0000u);
}
__device__ __forceinline__ unsigned encf(float x) {
    unsigned u = __float_as_uint(x);
    return (u & 0x80000000u) ? ~u : (u | 0x80000000u);
}
__device__ __forceinline__ float decf(unsigned e) {
    return __uint_as_float((e & 0x80000000u) ? (e ^ 0x80000000u) : ~e);
}

// ---------- 1. fused: zero cnt/gmax + cast x->bf16 (zero-pad) + weight prep ----------
__global__ void castprep_k(const float* __restrict__ x, unsigned short* __restrict__ xb,
                           const float* __restrict__ Wl1, const float* __restrict__ Wr1,
                           const float* __restrict__ bl1, const float* __restrict__ br1,
                           const float* __restrict__ Wl2, const float* __restrict__ Wr2,
                           const float* __restrict__ bl2, const float* __restrict__ br2,
                           unsigned short* __restrict__ Wt1, unsigned short* __restrict__ Wt2,
                           float* __restrict__ b1cat, float* __restrict__ b2cat,
                           int* __restrict__ cnt, unsigned* __restrict__ gmax) {
    int t = blockIdx.x * 256 + threadIdx.x;
    size_t base = (size_t)t * 4;
    if (base < (size_t)GNP * Ff) {
        ushort4 ov;
        if (base < (size_t)GN * Ff) {
            float4 v = *(const float4*)(x + base);
            ov.x = f2bf(v.x); ov.y = f2bf(v.y); ov.z = f2bf(v.z); ov.w = f2bf(v.w);
        } else {
            ov.x = ov.y = ov.z = ov.w = 0;
        }
        *(ushort4*)(xb + base) = ov;
    }
    if (t < 1024 * 128) {
        int n = t >> 7, k = t & 127;
        float v = (n < 512) ? Wl1[(size_t)k * 512 + n] : Wr1[(size_t)k * 512 + n - 512];
        Wt1[t] = f2bf(v);
    }
    if (t < 128 * 512) {
        int n = t >> 9, k = t & 511;
        float v = (n < 64) ? Wl2[(size_t)k * 64 + n] : Wr2[(size_t)k * 64 + n - 64];
        Wt2[t] = f2bf(v);
    }
    if (t < 1024) b1cat[t] = (t < 512) ? bl1[t] : br1[t - 512];
    if (t < 128)  b2cat[t] = (t < 64) ? bl2[t] : br2[t - 64];
    if (t < GN)   cnt[t] = 0;
    if (t < 1024) gmax[t] = 0u;
}

// ---------- 2. MFMA GEMM (gemm1): C(bf16) = A(bf16, lda) @ Bt^T + bias ----------
// EDGES=true additionally builds the padded CSR in its prologue (cnt pre-zeroed by castprep).
template <int K, bool EDGES>
__global__ __launch_bounds__(256) void mfma_gemm_k(const unsigned short* __restrict__ A, int lda,
                                                   const unsigned short* __restrict__ Bt,
                                                   const float* __restrict__ bias,
                                                   unsigned short* __restrict__ Cg, int ldc,
                                                   int Mreal,
                                                   const int* __restrict__ ei,
                                                   const float* __restrict__ ew,
                                                   int* __restrict__ cnt,
                                                   int2* __restrict__ sedge) {
    if (EDGES) {
        int bid = blockIdx.y * gridDim.x + blockIdx.x;
        int idx = bid * 256 + threadIdx.x;
        if (idx < Gg * Ee) {
            int g = (idx >= Ee) ? 1 : 0;
            int e = idx - g * Ee;
            int src = ei[(size_t)g * 2 * Ee + e];
            int dst = ei[(size_t)g * 2 * Ee + Ee + e];
            float wv = ew[idx];
            int node = g * Nn + dst;
            int pos = atomicAdd(&cnt[node], 1);
            if (pos < DEGMAX) {
                int2 v; v.x = src; v.y = __float_as_int(wv);
                sedge[(size_t)node * DEGMAX + pos] = v;
            }
        }
    }

    __shared__ unsigned short As[128 * 32];
    __shared__ unsigned short Bs[128 * 32];
    const int t = threadIdx.x;
    const int lane = t & 63;
    const int wid = t >> 6;
    const int wm = wid >> 1, wn = wid & 1;
    const int m0 = blockIdx.x * 128;
    const int n0 = blockIdx.y * 128;

    floatx4 acc[4][4] = {};

    const int jrow = t >> 2;
    const int js = t & 3;
    const int wavebase = (t & 192) * 16;

    for (int k0 = 0; k0 < K; k0 += 32) {
#pragma unroll
        for (int r = 0; r < 2; ++r) {
            int row = jrow + r * 64;
            int c = js ^ ((row >> 1) & 3);
            const unsigned short* gA = A + (size_t)(m0 + row) * lda + k0 + c * 8;
            const unsigned short* gB = Bt + (size_t)(n0 + row) * K + k0 + c * 8;
            __builtin_amdgcn_global_load_lds(
                (const __attribute__((address_space(1))) void*)gA,
                (__attribute__((address_space(3))) void*)((char*)As + r * 4096 + wavebase),
                16, 0, 0);
            __builtin_amdgcn_global_load_lds(
                (const __attribute__((address_space(1))) void*)gB,
                (__attribute__((address_space(3))) void*)((char*)Bs + r * 4096 + wavebase),
                16, 0, 0);
        }
        __syncthreads();

        const int lrow = lane & 15, lc = lane >> 4;
        short8 af[4], bf[4];
#pragma unroll
        for (int i2 = 0; i2 < 4; ++i2) {
            int rA = wm * 64 + i2 * 16 + lrow;
            int sA = lc ^ ((rA >> 1) & 3);
            af[i2] = *(const short8*)((const char*)As + (rA * 4 + sA) * 16);
        }
#pragma unroll
        for (int j2 = 0; j2 < 4; ++j2) {
            int rB = wn * 64 + j2 * 16 + lrow;
            int sB = lc ^ ((rB >> 1) & 3);
            bf[j2] = *(const short8*)((const char*)Bs + (rB * 4 + sB) * 16);
        }
#pragma unroll
        for (int i2 = 0; i2 < 4; ++i2)
#pragma unroll
            for (int j2 = 0; j2 < 4; ++j2)
                acc[i2][j2] = __builtin_amdgcn_mfma_f32_16x16x32_bf16(bf[j2], af[i2], acc[i2][j2], 0, 0, 0);
        __syncthreads();
    }

    const int mrow = m0 + wm * 64 + (lane & 15);
    const int ncol0 = n0 + wn * 64 + ((lane >> 4) << 2);
    float4 bq[4];
#pragma unroll
    for (int j2 = 0; j2 < 4; ++j2) bq[j2] = *(const float4*)(bias + ncol0 + j2 * 16);
#pragma unroll
    for (int i2 = 0; i2 < 4; ++i2) {
        int m = mrow + i2 * 16;
        if (m < Mreal) {
#pragma unroll
            for (int j2 = 0; j2 < 4; ++j2) {
                ushort4 ov;
                ov.x = f2bf(acc[i2][j2][0] + bq[j2].x);
                ov.y = f2bf(acc[i2][j2][1] + bq[j2].y);
                ov.z = f2bf(acc[i2][j2][2] + bq[j2].z);
                ov.w = f2bf(acc[i2][j2][3] + bq[j2].w);
                *(ushort4*)(Cg + (size_t)m * ldc + ncol0 + j2 * 16) = ov;
            }
        }
    }
}

// ---------- 2b. gemm2: 64(M)x128(N) tile, 128 threads = 2 waves of 64x64 ----------
__global__ __launch_bounds__(128) void gemm2_k(const unsigned short* __restrict__ A, int lda,
                                               const unsigned short* __restrict__ Bt,
                                               const float* __restrict__ bias,
                                               unsigned short* __restrict__ Cg,
                                               int Mreal) {
    __shared__ unsigned short As[64 * 32];   // 4 KB
    __shared__ unsigned short Bs[128 * 32];  // 8 KB
    const int t = threadIdx.x;
    const int lane = t & 63;
    const int wn = t >> 6;
    const int m0 = blockIdx.x * 64;

    floatx4 acc[4][4] = {};
    const int wavebase = (t & 64) * 16;

    for (int k0 = 0; k0 < HC; k0 += 32) {
#pragma unroll
        for (int it = 0; it < 2; ++it) {
            int slot = t + it * 128;
            int row = slot >> 2;
            int c = (slot & 3) ^ ((row >> 1) & 3);
            const unsigned short* gA = A + (size_t)(m0 + row) * lda + k0 + c * 8;
            __builtin_amdgcn_global_load_lds(
                (const __attribute__((address_space(1))) void*)gA,
                (__attribute__((address_space(3))) void*)((char*)As + it * 2048 + wavebase),
                16, 0, 0);
        }
#pragma unroll
        for (int it = 0; it < 4; ++it) {
            int slot = t + it * 128;
            int row = slot >> 2;
            int c = (slot & 3) ^ ((row >> 1) & 3);
            const unsigned short* gB = Bt + (size_t)row * HC + k0 + c * 8;
            __builtin_amdgcn_global_load_lds(
                (const __attribute__((address_space(1))) void*)gB,
                (__attribute__((address_space(3))) void*)((char*)Bs + it * 2048 + wavebase),
                16, 0, 0);
        }
        __syncthreads();

        const int lrow = lane & 15, lc = lane >> 4;
        short8 af[4], bf[4];
#pragma unroll
        for (int i2 = 0; i2 < 4; ++i2) {
            int rA = i2 * 16 + lrow;
            int sA = lc ^ ((rA >> 1) & 3);
            af[i2] = *(const short8*)((const char*)As + (rA * 4 + sA) * 16);
        }
#pragma unroll
        for (int j2 = 0; j2 < 4; ++j2) {
            int rB = wn * 64 + j2 * 16 + lrow;
            int sB = lc ^ ((rB >> 1) & 3);
            bf[j2] = *(const short8*)((const char*)Bs + (rB * 4 + sB) * 16);
        }
#pragma unroll
        for (int i2 = 0; i2 < 4; ++i2)
#pragma unroll
            for (int j2 = 0; j2 < 4; ++j2)
                acc[i2][j2] = __builtin_amdgcn_mfma_f32_16x16x32_bf16(bf[j2], af[i2], acc[i2][j2], 0, 0, 0);
        __syncthreads();
    }

    const int mrow = m0 + (lane & 15);
    const int ncol0 = wn * 64 + ((lane >> 4) << 2);
    float4 bq[4];
#pragma unroll
    for (int j2 = 0; j2 < 4; ++j2) bq[j2] = *(const float4*)(bias + ncol0 + j2 * 16);
#pragma unroll
    for (int i2 = 0; i2 < 4; ++i2) {
        int m = mrow + i2 * 16;
        if (m < Mreal) {
#pragma unroll
            for (int j2 = 0; j2 < 4; ++j2) {
                ushort4 ov;
                ov.x = f2bf(acc[i2][j2][0] + bq[j2].x);
                ov.y = f2bf(acc[i2][j2][1] + bq[j2].y);
                ov.z = f2bf(acc[i2][j2][2] + bq[j2].z);
                ov.w = f2bf(acc[i2][j2][3] + bq[j2].w);
                *(ushort4*)(Cg + (size_t)m * 128 + ncol0 + j2 * 16) = ov;
            }
        }
    }
}

// ---------- 3. GATv2 layer-1: one wave per node, pairwise + 2-pair prefetch.
// nbase splits the node range across two dispatches (diagnostic: surfaces the
// true #2 kernel in the top-5 profile; same total work).
__global__ __launch_bounds__(256) void agg1_k(const unsigned short* xlr,
                                              const int2* __restrict__ sedge,
                                              const int* __restrict__ cnt,
                                              const float* __restrict__ att1, const float* __restrict__ We1,
                                              const float* __restrict__ bias1,
                                              unsigned short* h1, float* __restrict__ loopw,
                                              int nbase) {
    const int lane = threadIdx.x & 63;
    const int node = nbase + (blockIdx.x << 2) + (threadIdx.x >> 6);
    const int g = (node >= Nn) ? 1 : 0;

    float attv[8], wev[8];
    {
        float4 a0 = *(const float4*)(att1 + lane * 8);
        float4 a1 = *(const float4*)(att1 + lane * 8 + 4);
        attv[0] = a0.x; attv[1] = a0.y; attv[2] = a0.z; attv[3] = a0.w;
        attv[4] = a1.x; attv[5] = a1.y; attv[6] = a1.z; attv[7] = a1.w;
        float4 w0 = *(const float4*)(We1 + lane * 8);
        float4 w1 = *(const float4*)(We1 + lane * 8 + 4);
        wev[0] = w0.x; wev[1] = w0.y; wev[2] = w0.z; wev[3] = w0.w;
        wev[4] = w1.x; wev[5] = w1.y; wev[6] = w1.z; wev[7] = w1.w;
    }
    float xrv[8];
    unpack8(((const uint4*)(xlr + (size_t)node * 1024 + 512))[lane], xrv);

    const int ec = cnt[node];
    const int2* ep = sedge + (size_t)node * DEGMAX;
    const uint4* rowb = (const uint4*)(xlr + (size_t)g * Nn * 1024) + lane;

    float lsum = 0.f, wsum = 0.f;
    float acc[8] = {};

    uint4 r0, r1; int2 s0v, s1v;
    if (ec > 0) { s0v = ep[0]; r0 = rowb[(size_t)s0v.x * 128]; }
    if (ec > 1) { s1v = ep[1]; r1 = rowb[(size_t)s1v.x * 128]; }
    int e = 0;
    while (e + 1 < ec) {
        uint4 r2, r3; int2 s2v, s3v;
        if (e + 2 < ec) { s2v = ep[e + 2]; r2 = rowb[(size_t)s2v.x * 128]; }
        if (e + 3 < ec) { s3v = ep[e + 3]; r3 = rowb[(size_t)s3v.x * 128]; }
        float xa[8], xb_[8];
        unpack8(r0, xa);
        unpack8(r1, xb_);
        float wa = __int_as_float(s0v.y), wb = __int_as_float(s1v.y);
        wsum += wa + wb;
        float ta = 0.f, tb = 0.f;
#pragma unroll
        for (int j = 0; j < 8; ++j) {
            float sa = xa[j] + fmaf(wa, wev[j], xrv[j]);
            float sb = xb_[j] + fmaf(wb, wev[j], xrv[j]);
            sa = fmaxf(sa, NEG_SLOPE * sa);
            sb = fmaxf(sb, NEG_SLOPE * sb);
            ta = fmaf(sa, attv[j], ta);
            tb = fmaf(sb, attv[j], tb);
        }
        ta += __shfl_xor(ta, 1); tb += __shfl_xor(tb, 1);
        ta += __shfl_xor(ta, 2); tb += __shfl_xor(tb, 2);
        ta += __shfl_xor(ta, 4); tb += __shfl_xor(tb, 4);
        float pa = __expf(ta), pb = __expf(tb);
        lsum += pa + pb;
#pragma unroll
        for (int j = 0; j < 8; ++j) acc[j] = fmaf(pa, xa[j], fmaf(pb, xb_[j], acc[j]));
        r0 = r2; s0v = s2v; r1 = r3; s1v = s3v;
        e += 2;
    }
    if (e < ec) {  // tail
        float xa[8];
        unpack8(r0, xa);
        float wa = __int_as_float(s0v.y);
        wsum += wa;
        float ta = 0.f;
#pragma unroll
        for (int j = 0; j < 8; ++j) {
            float sa = xa[j] + fmaf(wa, wev[j], xrv[j]);
            sa = fmaxf(sa, NEG_SLOPE * sa);
            ta = fmaf(sa, attv[j], ta);
        }
        ta += __shfl_xor(ta, 1); ta += __shfl_xor(ta, 2); ta += __shfl_xor(ta, 4);
        float pa = __expf(ta);
        lsum += pa;
#pragma unroll
        for (int j = 0; j < 8; ++j) acc[j] = fmaf(pa, xa[j], acc[j]);
    }

    // self loop (lw known only after the walk; raw-exp is order-independent)
    float lw = wsum / fmaxf((float)ec, 1.f);
    {
        float xv[8];
        unpack8(((const uint4*)(xlr + (size_t)node * 1024))[lane], xv);
        float tp = 0.f;
#pragma unroll
        for (int j = 0; j < 8; ++j) {
            float s = xv[j] + fmaf(lw, wev[j], xrv[j]);
            s = fmaxf(s, NEG_SLOPE * s);
            tp = fmaf(s, attv[j], tp);
        }
        tp += __shfl_xor(tp, 1); tp += __shfl_xor(tp, 2); tp += __shfl_xor(tp, 4);
        float p = __expf(tp);
        lsum += p;
#pragma unroll
        for (int j = 0; j < 8; ++j) acc[j] = fmaf(p, xv[j], acc[j]);
    }

    float inv = 1.f / lsum;
    float4 b0 = *(const float4*)(bias1 + lane * 8);
    float4 b1 = *(const float4*)(bias1 + lane * 8 + 4);
    float bvv[8] = {b0.x, b0.y, b0.z, b0.w, b1.x, b1.y, b1.z, b1.w};
    float ov[8];
#pragma unroll
    for (int j = 0; j < 8; ++j) {
        float o = fmaf(acc[j], inv, bvv[j]);
        ov[j] = o > 0.f ? o : (__expf(o) - 1.f);
    }
    uint4 pk;
    pk.x = (unsigned)f2bf(ov[0]) | ((unsigned)f2bf(ov[1]) << 16);
    pk.y = (unsigned)f2bf(ov[2]) | ((unsigned)f2bf(ov[3]) << 16);
    pk.z = (unsigned)f2bf(ov[4]) | ((unsigned)f2bf(ov[5]) << 16);
    pk.w = (unsigned)f2bf(ov[6]) | ((unsigned)f2bf(ov[7]) << 16);
    ((uint4*)(h1 + (size_t)node * 1024))[lane] = pk;
    if (lane == 0) loopw[node] = lw;
}

// ---------- 4. GATv2 layer-2: one node per wave, 4 x 16-lane subgroups; fused channel-max ----------
__global__ __launch_bounds__(1024) void agg2_k(const unsigned short* __restrict__ xlr2,
                                               const int2* __restrict__ sedge,
                                               const int* __restrict__ cnt,
                                               const float* __restrict__ loopw,
                                               const float* __restrict__ att2, const float* __restrict__ We2,
                                               const float* __restrict__ bias2,
                                               float* __restrict__ hout, unsigned* __restrict__ gmax) {
    const int tid = threadIdx.x;
    const int lane = tid & 63;
    const int cs = lane & 15;
    const int sub = lane >> 4;
    const int node = blockIdx.x * 16 + (tid >> 6);
    const int g = (node >= Nn) ? 1 : 0;

    float4 av = *(const float4*)(att2 + cs * 4);
    float4 wv4 = *(const float4*)(We2 + cs * 4);
    float attv[4] = {av.x, av.y, av.z, av.w};
    float wevv[4] = {wv4.x, wv4.y, wv4.z, wv4.w};
    float xrv[4];
    unpack4(*(const uint2*)(xlr2 + (size_t)node * 128 + 64 + cs * 4), xrv);
    const unsigned short* rowb = xlr2 + (size_t)g * Nn * 128;

    const int ec = cnt[node];
    const int2* ep = sedge + (size_t)node * DEGMAX;
    const int lo = (ec * sub) >> 2;
    const int hi = (ec * (sub + 1)) >> 2;

    float lsum = 0.f, acc[4] = {};

    int e = lo;
    uint2 r0 = {0, 0}, r1 = {0, 0};
    int2 s0v = {0, 0}, s1v = {0, 0};
    if (e < hi)     { s0v = ep[e];     r0 = *(const uint2*)(rowb + (size_t)s0v.x * 128 + cs * 4); }
    if (e + 1 < hi) { s1v = ep[e + 1]; r1 = *(const uint2*)(rowb + (size_t)s1v.x * 128 + cs * 4); }
    while (e + 1 < hi) {
        uint2 r2 = {0, 0}, r3 = {0, 0};
        int2 s2v = {0, 0}, s3v = {0, 0};
        if (e + 2 < hi) { s2v = ep[e + 2]; r2 = *(const uint2*)(rowb + (size_t)s2v.x * 128 + cs * 4); }
        if (e + 3 < hi) { s3v = ep[e + 3]; r3 = *(const uint2*)(rowb + (size_t)s3v.x * 128 + cs * 4); }
        float xa[4], xb_[4];
        unpack4(r0, xa);
        unpack4(r1, xb_);
        float wa = __int_as_float(s0v.y), wb = __int_as_float(s1v.y);
        float ta = 0.f, tb = 0.f;
#pragma unroll
        for (int j = 0; j < 4; ++j) {
            float sa = xa[j] + fmaf(wa, wevv[j], xrv[j]);
            float sb = xb_[j] + fmaf(wb, wevv[j], xrv[j]);
            sa = fmaxf(sa, NEG_SLOPE * sa);
            sb = fmaxf(sb, NEG_SLOPE * sb);
            ta = fmaf(sa, attv[j], ta);
            tb = fmaf(sb, attv[j], tb);
        }
        ta += __shfl_xor(ta, 1); tb += __shfl_xor(tb, 1);
        ta += __shfl_xor(ta, 2); tb += __shfl_xor(tb, 2);
        ta += __shfl_xor(ta, 4); tb += __shfl_xor(tb, 4);
        ta += __shfl_xor(ta, 8); tb += __shfl_xor(tb, 8);
        float pa = __expf(ta), pb = __expf(tb);
        lsum += pa + pb;
#pragma unroll
        for (int j = 0; j < 4; ++j) acc[j] = fmaf(pa, xa[j], fmaf(pb, xb_[j], acc[j]));
        r0 = r2; s0v = s2v; r1 = r3; s1v = s3v;
        e += 2;
    }
    if (e < hi) {
        float xa[4];
        unpack4(r0, xa);
        float wa = __int_as_float(s0v.y);
        float ta = 0.f;
#pragma unroll
        for (int j = 0; j < 4; ++j) {
            float sa = xa[j] + fmaf(wa, wevv[j], xrv[j]);
            sa = fmaxf(sa, NEG_SLOPE * sa);
            ta = fmaf(sa, attv[j], ta);
        }
        ta += __shfl_xor(ta, 1); ta += __shfl_xor(ta, 2);
        ta += __shfl_xor(ta, 4); ta += __shfl_xor(ta, 8);
        float pa = __expf(ta);
        lsum += pa;
#pragma unroll
        for (int j = 0; j < 4; ++j) acc[j] = fmaf(pa, xa[j], acc[j]);
    }

    lsum += __shfl_xor(lsum, 16); lsum += __shfl_xor(lsum, 32);
#pragma unroll
    for (int j = 0; j < 4; ++j) {
        acc[j] += __shfl_xor(acc[j], 16);
        acc[j] += __shfl_xor(acc[j], 32);
    }

    {
        float lw = loopw[node];
        float xv[4];
        unpack4(*(const uint2*)(xlr2 + (size_t)node * 128 + cs * 4), xv);
        float tp = 0.f;
#pragma unroll
        for (int j = 0; j < 4; ++j) {
            float s = xv[j] + fmaf(lw, wevv[j], xrv[j]);
            s = fmaxf(s, NEG_SLOPE * s);
            tp = fmaf(s, attv[j], tp);
        }
        tp += __shfl_xor(tp, 1); tp += __shfl_xor(tp, 2);
        tp += __shfl_xor(tp, 4); tp += __shfl_xor(tp, 8);
        float p = __expf(tp);
        lsum += p;
#pragma unroll
        for (int j = 0; j < 4; ++j) acc[j] = fmaf(p, xv[j], acc[j]);
    }

    float inv = 1.f / lsum;
    float4 bv = *(const float4*)(bias2 + cs * 4);
    float bvv[4] = {bv.x, bv.y, bv.z, bv.w};
    float ov[4];
#pragma unroll
    for (int j = 0; j < 4; ++j) {
        float o = fmaf(acc[j], inv, bvv[j]);
        ov[j] = o > 0.f ? o : (__expf(o) - 1.f);
    }
    if (sub == 0) {
        float4 o4;
        o4.x = ov[0]; o4.y = ov[1]; o4.z = ov[2]; o4.w = ov[3];
        *(float4*)(hout + (size_t)node * Cc + cs * 4) = o4;
    }

    __shared__ unsigned bm[64];
    if (tid < 64) bm[tid] = 0u;
    __syncthreads();
    if (sub == 0) {
#pragma unroll
        for (int j = 0; j < 4; ++j) atomicMax(&bm[cs * 4 + j], encf(ov[j]));
    }
    __syncthreads();
    if (tid < 64) atomicMax(&gmax[tid * 16], bm[tid]);
}

// ---------- 5. final: fused [Gv/cvec recompute] + relu(h@Wn[:64]+cvec)@Wo + bo ----------
// 64 nodes per block (4x fewer blocks -> 4x less Wn reload traffic).
__global__ __launch_bounds__(256) void final_k(const float* __restrict__ h,
                                               const unsigned* __restrict__ gmax,
                                               const float* __restrict__ Wg, const float* __restrict__ bg,
                                               const float* __restrict__ Wn, const float* __restrict__ bn,
                                               const float* __restrict__ Wo, const float* __restrict__ bo,
                                               float* __restrict__ out) {
    __shared__ float wns[64 * 64];
    __shared__ float g0s[64], g1s[64], cvs[64];
    const int tid = threadIdx.x;
    for (int k = tid; k < 64 * 64; k += 256) wns[k] = Wn[k];
    if (tid < 64) g0s[tid] = decf(gmax[tid * 16]);
    __syncthreads();
    if (tid < 64) {
        float a = bg[tid];
        for (int c = 0; c < 64; ++c) a += g0s[c] * Wg[c * 64 + tid];
        g1s[tid] = fmaxf(a, 0.f);
    }
    __syncthreads();
    if (tid < 64) {
        float b = bn[tid];
        for (int c = 0; c < 64; ++c) b += g1s[c] * Wn[(64 + c) * 64 + tid];
        cvs[tid] = b;
    }
    __syncthreads();

    const int lane = tid & 63;
    const int cs = lane & 15;
    const int sub = lane >> 4;
    float4 wo4 = *(const float4*)(Wo + cs * 4);
    float woa[4] = {wo4.x, wo4.y, wo4.z, wo4.w};
    float cv0 = cvs[cs * 4 + 0], cv1 = cvs[cs * 4 + 1], cv2 = cvs[cs * 4 + 2], cv3 = cvs[cs * 4 + 3];
    float bo0 = bo[0];

#pragma unroll
    for (int nb = 0; nb < 4; ++nb) {
        const int node = blockIdx.x * 64 + nb * 16 + (tid >> 6) * 4 + sub;
        float4 h4 = *(const float4*)(h + (size_t)node * Cc + cs * 4);
        float hv[4] = {h4.x, h4.y, h4.z, h4.w};
        float inner[4] = {cv0, cv1, cv2, cv3};
#pragma unroll
        for (int c = 0; c < 64; ++c) {
            float hc = __shfl(hv[c & 3], sub * 16 + (c >> 2));
            float4 wv = *(const float4*)&wns[c * 64 + cs * 4];
            inner[0] = fmaf(hc, wv.x, inner[0]);
            inner[1] = fmaf(hc, wv.y, inner[1]);
            inner[2] = fmaf(hc, wv.z, inner[2]);
            inner[3] = fmaf(hc, wv.w, inner[3]);
        }
        float t = 0.f;
#pragma unroll
        for (int j = 0; j < 4; ++j) {
            float v = fmaxf(inner[j], 0.f);
            t = fmaf(v, woa[j], t);
        }
        t += __shfl_xor(t, 1); t += __shfl_xor(t, 2);
        t += __shfl_xor(t, 4); t += __shfl_xor(t, 8);
        if (cs == 0) out[node] = t + bo0;
    }
}

// ---------- launch ----------
extern "C" void kernel_launch(void* const* d_in, const int* in_sizes, int n_in,
                              void* d_out, int out_size, void* d_ws, size_t ws_size,
                              hipStream_t stream) {
    const float* x     = (const float*)d_in[0];
    const int*   ei    = (const int*)d_in[1];
    const float* ew    = (const float*)d_in[2];
    const float* Wl1   = (const float*)d_in[3];
    const float* bl1v  = (const float*)d_in[4];
    const float* Wr1   = (const float*)d_in[5];
    const float* br1v  = (const float*)d_in[6];
    const float* We1   = (const float*)d_in[7];
    const float* att1  = (const float*)d_in[8];
    const float* bias1 = (const float*)d_in[9];
    const float* Wl2   = (const float*)d_in[10];
    const float* bl2v  = (const float*)d_in[11];
    const float* Wr2   = (const float*)d_in[12];
    const float* br2v  = (const float*)d_in[13];
    const float* We2   = (const float*)d_in[14];
    const float* att2  = (const float*)d_in[15];
    const float* bias2 = (const float*)d_in[16];
    const float* Wg    = (const float*)d_in[17];
    const float* bgv   = (const float*)d_in[18];
    const float* Wn    = (const float*)d_in[19];
    const float* bnv   = (const float*)d_in[20];
    const float* Wo    = (const float*)d_in[21];
    const float* bov   = (const float*)d_in[22];
    float* out = (float*)d_out;

    char* w = (char*)d_ws;
    size_t o = 0;
    auto take = [&](size_t b) -> char* {
        char* p = w + o;
        o += (b + 255) & ~(size_t)255;
        return p;
    };
    unsigned short* xlr1 = (unsigned short*)take((size_t)GNP * 1024 * 2);     // 82 MB
    unsigned short* xb   = (unsigned short*)take((size_t)GNP * Ff * 2);       // 10.26 MB
    unsigned short* xlr2 = (unsigned short*)take((size_t)GNP * 128 * 2);      // 10.26 MB
    unsigned short* Wt1  = (unsigned short*)take(1024 * 128 * 2);
    unsigned short* Wt2  = (unsigned short*)take(128 * 512 * 2);
    float* b1cat = (float*)take(1024 * 4);
    float* b2cat = (float*)take(128 * 4);
    int*    cnt   = (int*)take((size_t)GN * 4);
    float*  loopw = (float*)take((size_t)GN * 4);
    int2*   sedge = (int2*)take((size_t)GN * DEGMAX * 8);                     // 15.36 MB
    unsigned* gmax = (unsigned*)take(1024 * 4);
    // overlays
    unsigned short* h1 = xlr1 + 512; // row stride 1024, aliases xr half
    float* hbuf = (float*)xb;        // xb dead after gemm1

    castprep_k<<<((GNP * Ff / 4) + 255) / 256, 256, 0, stream>>>(
        x, xb, Wl1, Wr1, bl1v, br1v, Wl2, Wr2, bl2v, br2v, Wt1, Wt2, b1cat, b2cat, cnt, gmax);

    // gemm1 also builds the padded CSR (2504 blocks x 256 = 641k threads >= 320k edges)
    mfma_gemm_k<Ff, true><<<dim3(GNP / 128, 8), 256, 0, stream>>>(
        xb, Ff, Wt1, b1cat, xlr1, 1024, GN, ei, ew, cnt, sedge);

    // agg1 split into two half-range dispatches (diagnostic; same total work)
    agg1_k<<<GN / 8, 256, 0, stream>>>(xlr1, sedge, cnt, att1, We1, bias1, h1, loopw, 0);
    agg1_k<<<GN / 8, 256, 0, stream>>>(xlr1, sedge, cnt, att1, We1, bias1, h1, loopw, GN / 2);

    gemm2_k<<<GNP / 64, 128, 0, stream>>>(h1, 1024, Wt2, b2cat, xlr2, GN);

    agg2_k<<<GN / 16, 1024, 0, stream>>>(xlr2, sedge, cnt, loopw, att2, We2, bias2, hbuf, gmax);

    final_k<<<GN / 64, 256, 0, stream>>>(hbuf, gmax, Wg, bgv, Wn, bnv, Wo, bov, out);

    (void)in_sizes; (void)n_in; (void)out_size; (void)ws_size;
}

// Round 13
// 329.475 us; speedup vs baseline: 1.0313x; 1.0313x over previous
//
#include <hip/hip_runtime.h>
#include <hip/hip_bf16.h>
#include <cstdint>
#include <cstddef>

#define NEG_SLOPE 0.2f

static constexpr int Gg = 2;
static constexpr int Nn = 20000;
static constexpr int Ee = 160000;
static constexpr int Ff = 128;
static constexpr int Cc = 64;
static constexpr int HC = 512;
static constexpr int GN = Gg * Nn;
static constexpr int GNP = 40064;  // GN padded to 128 multiple
static constexpr int DEGMAX = 48;  // padded CSR stride; P(deg>48) ~ 1e-20 (Poisson mean 8)

typedef __attribute__((ext_vector_type(8))) short short8;
typedef __attribute__((ext_vector_type(4))) float floatx4;

// ---------- helpers ----------
__device__ __forceinline__ float bf2f(unsigned short b) {
    return __uint_as_float(((unsigned)b) << 16);
}
__device__ __forceinline__ unsigned short f2bf(float x) {
    unsigned u = __float_as_uint(x);
    unsigned r = 0x7fffu + ((u >> 16) & 1u);
    return (unsigned short)((u + r) >> 16);
}
__device__ __forceinline__ void unpack8(const uint4 p, float* f) {
    f[0] = __uint_as_float(p.x << 16); f[1] = __uint_as_float(p.x & 0xffff0000u);
    f[2] = __uint_as_float(p.y << 16); f[3] = __uint_as_float(p.y & 0xffff0000u);
    f[4] = __uint_as_float(p.z << 16); f[5] = __uint_as_float(p.z & 0xffff0000u);
    f[6] = __uint_as_float(p.w << 16); f[7] = __uint_as_float(p.w & 0xffff0000u);
}
__device__ __forceinline__ void unpack4(const uint2 p, float* f) {
    f[0] = __uint_as_float(p.x << 16); f[1] = __uint_as_float(p.x & 0xffff0000u);
    f[2] = __uint_as_float(p.y << 16); f[3] = __uint_as_float(p.y & 0xffff0000u);
}
__device__ __forceinline__ unsigned encf(float x) {
    unsigned u = __float_as_uint(x);
    return (u & 0x80000000u) ? ~u : (u | 0x80000000u);
}
__device__ __forceinline__ float decf(unsigned e) {
    return __uint_as_float((e & 0x80000000u) ? (e ^ 0x80000000u) : ~e);
}

// ---------- 1. fused: zero gmax + cast x->bf16 (zero-pad) + weight prep + CSR build ----------
// cnt is zeroed by hipMemsetAsync BEFORE this kernel (can't zero+atomic in one kernel).
__global__ void castprep_k(const float* __restrict__ x, unsigned short* __restrict__ xb,
                           const float* __restrict__ Wl1, const float* __restrict__ Wr1,
                           const float* __restrict__ bl1, const float* __restrict__ br1,
                           const float* __restrict__ Wl2, const float* __restrict__ Wr2,
                           const float* __restrict__ bl2, const float* __restrict__ br2,
                           unsigned short* __restrict__ Wt1, unsigned short* __restrict__ Wt2,
                           float* __restrict__ b1cat, float* __restrict__ b2cat,
                           int* __restrict__ cnt, unsigned* __restrict__ gmax,
                           const int* __restrict__ ei, const float* __restrict__ ew,
                           int2* __restrict__ sedge) {
    int t = blockIdx.x * 256 + threadIdx.x;
    size_t base = (size_t)t * 4;
    if (base < (size_t)GNP * Ff) {
        ushort4 ov;
        if (base < (size_t)GN * Ff) {
            float4 v = *(const float4*)(x + base);
            ov.x = f2bf(v.x); ov.y = f2bf(v.y); ov.z = f2bf(v.z); ov.w = f2bf(v.w);
        } else {
            ov.x = ov.y = ov.z = ov.w = 0;
        }
        *(ushort4*)(xb + base) = ov;
    }
    if (t < 1024 * 128) {
        int n = t >> 7, k = t & 127;
        float v = (n < 512) ? Wl1[(size_t)k * 512 + n] : Wr1[(size_t)k * 512 + n - 512];
        Wt1[t] = f2bf(v);
    }
    if (t < 128 * 512) {
        int n = t >> 9, k = t & 511;
        float v = (n < 64) ? Wl2[(size_t)k * 64 + n] : Wr2[(size_t)k * 64 + n - 64];
        Wt2[t] = f2bf(v);
    }
    if (t < 1024) b1cat[t] = (t < 512) ? bl1[t] : br1[t - 512];
    if (t < 128)  b2cat[t] = (t < 64) ? bl2[t] : br2[t - 64];
    if (t < 1024) gmax[t] = 0u;
    if (t < Gg * Ee) {  // padded-CSR build
        int g = (t >= Ee) ? 1 : 0;
        int e = t - g * Ee;
        int src = ei[(size_t)g * 2 * Ee + e];
        int dst = ei[(size_t)g * 2 * Ee + Ee + e];
        float wv = ew[t];
        int node = g * Nn + dst;
        int pos = atomicAdd(&cnt[node], 1);
        if (pos < DEGMAX) {
            int2 v; v.x = src; v.y = __float_as_int(wv);
            sedge[(size_t)node * DEGMAX + pos] = v;
        }
    }
}

// ---------- 2. gemm1: single-stage BK=128 (whole K), ONE barrier ----------
// A [GNP][128], Bt [1024][128], C=xlr1 [GNP][1024]. 128x128 tile, 4 waves of 64x64.
// LDS 64 KB (2 blocks/CU). 16-slot XOR chunk swizzle: slot = c ^ (row & 15).
__global__ __launch_bounds__(256) void gemm1_k(const unsigned short* __restrict__ A,
                                               const unsigned short* __restrict__ Bt,
                                               const float* __restrict__ bias,
                                               unsigned short* __restrict__ Cg,
                                               int Mreal) {
    __shared__ unsigned short As[128 * 128];  // 32 KB
    __shared__ unsigned short Bs[128 * 128];  // 32 KB
    const int t = threadIdx.x;
    const int lane = t & 63;
    const int wid = t >> 6;
    const int wm = wid >> 1, wn = wid & 1;
    const int m0 = blockIdx.x * 128;
    const int n0 = blockIdx.y * 128;

    // stage full A and B tiles: 2048 chunks each, 8 per thread, all in flight
#pragma unroll
    for (int it = 0; it < 8; ++it) {
        int slin = t + it * 256;         // 0..2047
        int row = slin >> 4;
        int sc = slin & 15;
        int c = sc ^ (row & 15);
        const unsigned short* gA = A + (size_t)(m0 + row) * Ff + c * 8;
        const unsigned short* gB = Bt + (size_t)(n0 + row) * Ff + c * 8;
        int ldsbase = (it * 256 + (t & 192)) * 16;  // wave-uniform byte base
        __builtin_amdgcn_global_load_lds(
            (const __attribute__((address_space(1))) void*)gA,
            (__attribute__((address_space(3))) void*)((char*)As + ldsbase),
            16, 0, 0);
        __builtin_amdgcn_global_load_lds(
            (const __attribute__((address_space(1))) void*)gB,
            (__attribute__((address_space(3))) void*)((char*)Bs + ldsbase),
            16, 0, 0);
    }
    __syncthreads();

    floatx4 acc[4][4] = {};
    const int lrow = lane & 15, lc = lane >> 4;
#pragma unroll
    for (int k0 = 0; k0 < 4; ++k0) {
        short8 af[4], bf[4];
#pragma unroll
        for (int i2 = 0; i2 < 4; ++i2) {
            int rA = wm * 64 + i2 * 16 + lrow;
            int slot = (k0 * 4 + lc) ^ (rA & 15);
            af[i2] = *(const short8*)((const char*)As + rA * 256 + slot * 16);
        }
#pragma unroll
        for (int j2 = 0; j2 < 4; ++j2) {
            int rB = wn * 64 + j2 * 16 + lrow;
            int slot = (k0 * 4 + lc) ^ (rB & 15);
            bf[j2] = *(const short8*)((const char*)Bs + rB * 256 + slot * 16);
        }
#pragma unroll
        for (int i2 = 0; i2 < 4; ++i2)
#pragma unroll
            for (int j2 = 0; j2 < 4; ++j2)
                acc[i2][j2] = __builtin_amdgcn_mfma_f32_16x16x32_bf16(bf[j2], af[i2], acc[i2][j2], 0, 0, 0);
    }

    // epilogue (operand-swapped): m = lane&15 + i2*16, n = (lane>>4)*4 (+j2*16), packed ushort4
    const int mrow = m0 + wm * 64 + lrow;
    const int ncol0 = n0 + wn * 64 + (lc << 2);
    float4 bq[4];
#pragma unroll
    for (int j2 = 0; j2 < 4; ++j2) bq[j2] = *(const float4*)(bias + ncol0 + j2 * 16);
#pragma unroll
    for (int i2 = 0; i2 < 4; ++i2) {
        int m = mrow + i2 * 16;
        if (m < Mreal) {
#pragma unroll
            for (int j2 = 0; j2 < 4; ++j2) {
                ushort4 ov;
                ov.x = f2bf(acc[i2][j2][0] + bq[j2].x);
                ov.y = f2bf(acc[i2][j2][1] + bq[j2].y);
                ov.z = f2bf(acc[i2][j2][2] + bq[j2].z);
                ov.w = f2bf(acc[i2][j2][3] + bq[j2].w);
                *(ushort4*)(Cg + (size_t)m * 1024 + ncol0 + j2 * 16) = ov;
            }
        }
    }
}

// ---------- 2b. gemm2: 64(M)x128(N) tile, 128 threads = 2 waves of 64x64 ----------
__global__ __launch_bounds__(128) void gemm2_k(const unsigned short* __restrict__ A, int lda,
                                               const unsigned short* __restrict__ Bt,
                                               const float* __restrict__ bias,
                                               unsigned short* __restrict__ Cg,
                                               int Mreal) {
    __shared__ unsigned short As[64 * 32];   // 4 KB
    __shared__ unsigned short Bs[128 * 32];  // 8 KB
    const int t = threadIdx.x;
    const int lane = t & 63;
    const int wn = t >> 6;
    const int m0 = blockIdx.x * 64;

    floatx4 acc[4][4] = {};
    const int wavebase = (t & 64) * 16;

    for (int k0 = 0; k0 < HC; k0 += 32) {
#pragma unroll
        for (int it = 0; it < 2; ++it) {
            int slot = t + it * 128;
            int row = slot >> 2;
            int c = (slot & 3) ^ ((row >> 1) & 3);
            const unsigned short* gA = A + (size_t)(m0 + row) * lda + k0 + c * 8;
            __builtin_amdgcn_global_load_lds(
                (const __attribute__((address_space(1))) void*)gA,
                (__attribute__((address_space(3))) void*)((char*)As + it * 2048 + wavebase),
                16, 0, 0);
        }
#pragma unroll
        for (int it = 0; it < 4; ++it) {
            int slot = t + it * 128;
            int row = slot >> 2;
            int c = (slot & 3) ^ ((row >> 1) & 3);
            const unsigned short* gB = Bt + (size_t)row * HC + k0 + c * 8;
            __builtin_amdgcn_global_load_lds(
                (const __attribute__((address_space(1))) void*)gB,
                (__attribute__((address_space(3))) void*)((char*)Bs + it * 2048 + wavebase),
                16, 0, 0);
        }
        __syncthreads();

        const int lrow = lane & 15, lc = lane >> 4;
        short8 af[4], bf[4];
#pragma unroll
        for (int i2 = 0; i2 < 4; ++i2) {
            int rA = i2 * 16 + lrow;
            int sA = lc ^ ((rA >> 1) & 3);
            af[i2] = *(const short8*)((const char*)As + (rA * 4 + sA) * 16);
        }
#pragma unroll
        for (int j2 = 0; j2 < 4; ++j2) {
            int rB = wn * 64 + j2 * 16 + lrow;
            int sB = lc ^ ((rB >> 1) & 3);
            bf[j2] = *(const short8*)((const char*)Bs + (rB * 4 + sB) * 16);
        }
#pragma unroll
        for (int i2 = 0; i2 < 4; ++i2)
#pragma unroll
            for (int j2 = 0; j2 < 4; ++j2)
                acc[i2][j2] = __builtin_amdgcn_mfma_f32_16x16x32_bf16(bf[j2], af[i2], acc[i2][j2], 0, 0, 0);
        __syncthreads();
    }

    const int mrow = m0 + (lane & 15);
    const int ncol0 = wn * 64 + ((lane >> 4) << 2);
    float4 bq[4];
#pragma unroll
    for (int j2 = 0; j2 < 4; ++j2) bq[j2] = *(const float4*)(bias + ncol0 + j2 * 16);
#pragma unroll
    for (int i2 = 0; i2 < 4; ++i2) {
        int m = mrow + i2 * 16;
        if (m < Mreal) {
#pragma unroll
            for (int j2 = 0; j2 < 4; ++j2) {
                ushort4 ov;
                ov.x = f2bf(acc[i2][j2][0] + bq[j2].x);
                ov.y = f2bf(acc[i2][j2][1] + bq[j2].y);
                ov.z = f2bf(acc[i2][j2][2] + bq[j2].z);
                ov.w = f2bf(acc[i2][j2][3] + bq[j2].w);
                *(ushort4*)(Cg + (size_t)m * 128 + ncol0 + j2 * 16) = ov;
            }
        }
    }
}

// ---------- 3. GATv2 layer-1: one wave per node, pairwise + 2-pair prefetch ----------
__global__ __launch_bounds__(256) void agg1_k(const unsigned short* xlr,
                                              const int2* __restrict__ sedge,
                                              const int* __restrict__ cnt,
                                              const float* __restrict__ att1, const float* __restrict__ We1,
                                              const float* __restrict__ bias1,
                                              unsigned short* h1, float* __restrict__ loopw) {
    const int lane = threadIdx.x & 63;
    const int node = (blockIdx.x << 2) + (threadIdx.x >> 6);
    if (node >= GN) return;
    const int g = (node >= Nn) ? 1 : 0;

    float attv[8], wev[8];
    {
        float4 a0 = *(const float4*)(att1 + lane * 8);
        float4 a1 = *(const float4*)(att1 + lane * 8 + 4);
        attv[0] = a0.x; attv[1] = a0.y; attv[2] = a0.z; attv[3] = a0.w;
        attv[4] = a1.x; attv[5] = a1.y; attv[6] = a1.z; attv[7] = a1.w;
        float4 w0 = *(const float4*)(We1 + lane * 8);
        float4 w1 = *(const float4*)(We1 + lane * 8 + 4);
        wev[0] = w0.x; wev[1] = w0.y; wev[2] = w0.z; wev[3] = w0.w;
        wev[4] = w1.x; wev[5] = w1.y; wev[6] = w1.z; wev[7] = w1.w;
    }
    float xrv[8];
    unpack8(((const uint4*)(xlr + (size_t)node * 1024 + 512))[lane], xrv);

    const int ec = cnt[node];
    const int2* ep = sedge + (size_t)node * DEGMAX;
    const uint4* rowb = (const uint4*)(xlr + (size_t)g * Nn * 1024) + lane;

    float lsum = 0.f, wsum = 0.f;
    float acc[8] = {};

    uint4 r0, r1; int2 s0v, s1v;
    if (ec > 0) { s0v = ep[0]; r0 = rowb[(size_t)s0v.x * 128]; }
    if (ec > 1) { s1v = ep[1]; r1 = rowb[(size_t)s1v.x * 128]; }
    int e = 0;
    while (e + 1 < ec) {
        uint4 r2, r3; int2 s2v, s3v;
        if (e + 2 < ec) { s2v = ep[e + 2]; r2 = rowb[(size_t)s2v.x * 128]; }
        if (e + 3 < ec) { s3v = ep[e + 3]; r3 = rowb[(size_t)s3v.x * 128]; }
        float xa[8], xb_[8];
        unpack8(r0, xa);
        unpack8(r1, xb_);
        float wa = __int_as_float(s0v.y), wb = __int_as_float(s1v.y);
        wsum += wa + wb;
        float ta = 0.f, tb = 0.f;
#pragma unroll
        for (int j = 0; j < 8; ++j) {
            float sa = xa[j] + fmaf(wa, wev[j], xrv[j]);
            float sb = xb_[j] + fmaf(wb, wev[j], xrv[j]);
            sa = fmaxf(sa, NEG_SLOPE * sa);
            sb = fmaxf(sb, NEG_SLOPE * sb);
            ta = fmaf(sa, attv[j], ta);
            tb = fmaf(sb, attv[j], tb);
        }
        ta += __shfl_xor(ta, 1); tb += __shfl_xor(tb, 1);
        ta += __shfl_xor(ta, 2); tb += __shfl_xor(tb, 2);
        ta += __shfl_xor(ta, 4); tb += __shfl_xor(tb, 4);
        float pa = __expf(ta), pb = __expf(tb);
        lsum += pa + pb;
#pragma unroll
        for (int j = 0; j < 8; ++j) acc[j] = fmaf(pa, xa[j], fmaf(pb, xb_[j], acc[j]));
        r0 = r2; s0v = s2v; r1 = r3; s1v = s3v;
        e += 2;
    }
    if (e < ec) {  // tail
        float xa[8];
        unpack8(r0, xa);
        float wa = __int_as_float(s0v.y);
        wsum += wa;
        float ta = 0.f;
#pragma unroll
        for (int j = 0; j < 8; ++j) {
            float sa = xa[j] + fmaf(wa, wev[j], xrv[j]);
            sa = fmaxf(sa, NEG_SLOPE * sa);
            ta = fmaf(sa, attv[j], ta);
        }
        ta += __shfl_xor(ta, 1); ta += __shfl_xor(ta, 2); ta += __shfl_xor(ta, 4);
        float pa = __expf(ta);
        lsum += pa;
#pragma unroll
        for (int j = 0; j < 8; ++j) acc[j] = fmaf(pa, xa[j], acc[j]);
    }

    // self loop (lw known only after the walk; raw-exp is order-independent)
    float lw = wsum / fmaxf((float)ec, 1.f);
    {
        float xv[8];
        unpack8(((const uint4*)(xlr + (size_t)node * 1024))[lane], xv);
        float tp = 0.f;
#pragma unroll
        for (int j = 0; j < 8; ++j) {
            float s = xv[j] + fmaf(lw, wev[j], xrv[j]);
            s = fmaxf(s, NEG_SLOPE * s);
            tp = fmaf(s, attv[j], tp);
        }
        tp += __shfl_xor(tp, 1); tp += __shfl_xor(tp, 2); tp += __shfl_xor(tp, 4);
        float p = __expf(tp);
        lsum += p;
#pragma unroll
        for (int j = 0; j < 8; ++j) acc[j] = fmaf(p, xv[j], acc[j]);
    }

    float inv = 1.f / lsum;
    float4 b0 = *(const float4*)(bias1 + lane * 8);
    float4 b1 = *(const float4*)(bias1 + lane * 8 + 4);
    float bvv[8] = {b0.x, b0.y, b0.z, b0.w, b1.x, b1.y, b1.z, b1.w};
    float ov[8];
#pragma unroll
    for (int j = 0; j < 8; ++j) {
        float o = fmaf(acc[j], inv, bvv[j]);
        ov[j] = o > 0.f ? o : (__expf(o) - 1.f);
    }
    uint4 pk;
    pk.x = (unsigned)f2bf(ov[0]) | ((unsigned)f2bf(ov[1]) << 16);
    pk.y = (unsigned)f2bf(ov[2]) | ((unsigned)f2bf(ov[3]) << 16);
    pk.z = (unsigned)f2bf(ov[4]) | ((unsigned)f2bf(ov[5]) << 16);
    pk.w = (unsigned)f2bf(ov[6]) | ((unsigned)f2bf(ov[7]) << 16);
    ((uint4*)(h1 + (size_t)node * 1024))[lane] = pk;
    if (lane == 0) loopw[node] = lw;
}

// ---------- 4. GATv2 layer-2: one node per wave, 4 x 16-lane subgroups; fused channel-max ----------
__global__ __launch_bounds__(1024) void agg2_k(const unsigned short* __restrict__ xlr2,
                                               const int2* __restrict__ sedge,
                                               const int* __restrict__ cnt,
                                               const float* __restrict__ loopw,
                                               const float* __restrict__ att2, const float* __restrict__ We2,
                                               const float* __restrict__ bias2,
                                               float* __restrict__ hout, unsigned* __restrict__ gmax) {
    const int tid = threadIdx.x;
    const int lane = tid & 63;
    const int cs = lane & 15;
    const int sub = lane >> 4;
    const int node = blockIdx.x * 16 + (tid >> 6);
    const int g = (node >= Nn) ? 1 : 0;

    float4 av = *(const float4*)(att2 + cs * 4);
    float4 wv4 = *(const float4*)(We2 + cs * 4);
    float attv[4] = {av.x, av.y, av.z, av.w};
    float wevv[4] = {wv4.x, wv4.y, wv4.z, wv4.w};
    float xrv[4];
    unpack4(*(const uint2*)(xlr2 + (size_t)node * 128 + 64 + cs * 4), xrv);
    const unsigned short* rowb = xlr2 + (size_t)g * Nn * 128;

    const int ec = cnt[node];
    const int2* ep = sedge + (size_t)node * DEGMAX;
    const int lo = (ec * sub) >> 2;
    const int hi = (ec * (sub + 1)) >> 2;

    float lsum = 0.f, acc[4] = {};

    int e = lo;
    uint2 r0 = {0, 0}, r1 = {0, 0};
    int2 s0v = {0, 0}, s1v = {0, 0};
    if (e < hi)     { s0v = ep[e];     r0 = *(const uint2*)(rowb + (size_t)s0v.x * 128 + cs * 4); }
    if (e + 1 < hi) { s1v = ep[e + 1]; r1 = *(const uint2*)(rowb + (size_t)s1v.x * 128 + cs * 4); }
    while (e + 1 < hi) {
        uint2 r2 = {0, 0}, r3 = {0, 0};
        int2 s2v = {0, 0}, s3v = {0, 0};
        if (e + 2 < hi) { s2v = ep[e + 2]; r2 = *(const uint2*)(rowb + (size_t)s2v.x * 128 + cs * 4); }
        if (e + 3 < hi) { s3v = ep[e + 3]; r3 = *(const uint2*)(rowb + (size_t)s3v.x * 128 + cs * 4); }
        float xa[4], xb_[4];
        unpack4(r0, xa);
        unpack4(r1, xb_);
        float wa = __int_as_float(s0v.y), wb = __int_as_float(s1v.y);
        float ta = 0.f, tb = 0.f;
#pragma unroll
        for (int j = 0; j < 4; ++j) {
            float sa = xa[j] + fmaf(wa, wevv[j], xrv[j]);
            float sb = xb_[j] + fmaf(wb, wevv[j], xrv[j]);
            sa = fmaxf(sa, NEG_SLOPE * sa);
            sb = fmaxf(sb, NEG_SLOPE * sb);
            ta = fmaf(sa, attv[j], ta);
            tb = fmaf(sb, attv[j], tb);
        }
        ta += __shfl_xor(ta, 1); tb += __shfl_xor(tb, 1);
        ta += __shfl_xor(ta, 2); tb += __shfl_xor(tb, 2);
        ta += __shfl_xor(ta, 4); tb += __shfl_xor(tb, 4);
        ta += __shfl_xor(ta, 8); tb += __shfl_xor(tb, 8);
        float pa = __expf(ta), pb = __expf(tb);
        lsum += pa + pb;
#pragma unroll
        for (int j = 0; j < 4; ++j) acc[j] = fmaf(pa, xa[j], fmaf(pb, xb_[j], acc[j]));
        r0 = r2; s0v = s2v; r1 = r3; s1v = s3v;
        e += 2;
    }
    if (e < hi) {
        float xa[4];
        unpack4(r0, xa);
        float wa = __int_as_float(s0v.y);
        float ta = 0.f;
#pragma unroll
        for (int j = 0; j < 4; ++j) {
            float sa = xa[j] + fmaf(wa, wevv[j], xrv[j]);
            sa = fmaxf(sa, NEG_SLOPE * sa);
            ta = fmaf(sa, attv[j], ta);
        }
        ta += __shfl_xor(ta, 1); ta += __shfl_xor(ta, 2);
        ta += __shfl_xor(ta, 4); ta += __shfl_xor(ta, 8);
        float pa = __expf(ta);
        lsum += pa;
#pragma unroll
        for (int j = 0; j < 4; ++j) acc[j] = fmaf(pa, xa[j], acc[j]);
    }

    lsum += __shfl_xor(lsum, 16); lsum += __shfl_xor(lsum, 32);
#pragma unroll
    for (int j = 0; j < 4; ++j) {
        acc[j] += __shfl_xor(acc[j], 16);
        acc[j] += __shfl_xor(acc[j], 32);
    }

    {
        float lw = loopw[node];
        float xv[4];
        unpack4(*(const uint2*)(xlr2 + (size_t)node * 128 + cs * 4), xv);
        float tp = 0.f;
#pragma unroll
        for (int j = 0; j < 4; ++j) {
            float s = xv[j] + fmaf(lw, wevv[j], xrv[j]);
            s = fmaxf(s, NEG_SLOPE * s);
            tp = fmaf(s, attv[j], tp);
        }
        tp += __shfl_xor(tp, 1); tp += __shfl_xor(tp, 2);
        tp += __shfl_xor(tp, 4); tp += __shfl_xor(tp, 8);
        float p = __expf(tp);
        lsum += p;
#pragma unroll
        for (int j = 0; j < 4; ++j) acc[j] = fmaf(p, xv[j], acc[j]);
    }

    float inv = 1.f / lsum;
    float4 bv = *(const float4*)(bias2 + cs * 4);
    float bvv[4] = {bv.x, bv.y, bv.z, bv.w};
    float ov[4];
#pragma unroll
    for (int j = 0; j < 4; ++j) {
        float o = fmaf(acc[j], inv, bvv[j]);
        ov[j] = o > 0.f ? o : (__expf(o) - 1.f);
    }
    if (sub == 0) {
        float4 o4;
        o4.x = ov[0]; o4.y = ov[1]; o4.z = ov[2]; o4.w = ov[3];
        *(float4*)(hout + (size_t)node * Cc + cs * 4) = o4;
    }

    __shared__ unsigned bm[64];
    if (tid < 64) bm[tid] = 0u;
    __syncthreads();
    if (sub == 0) {
#pragma unroll
        for (int j = 0; j < 4; ++j) atomicMax(&bm[cs * 4 + j], encf(ov[j]));
    }
    __syncthreads();
    if (tid < 64) atomicMax(&gmax[tid * 16], bm[tid]);
}

// ---------- 5. final: fused [Gv/cvec recompute] + relu(h@Wn[:64]+cvec)@Wo + bo ----------
// 64 nodes per block.
__global__ __launch_bounds__(256) void final_k(const float* __restrict__ h,
                                               const unsigned* __restrict__ gmax,
                                               const float* __restrict__ Wg, const float* __restrict__ bg,
                                               const float* __restrict__ Wn, const float* __restrict__ bn,
                                               const float* __restrict__ Wo, const float* __restrict__ bo,
                                               float* __restrict__ out) {
    __shared__ float wns[64 * 64];
    __shared__ float g0s[64], g1s[64], cvs[64];
    const int tid = threadIdx.x;
    for (int k = tid; k < 64 * 64; k += 256) wns[k] = Wn[k];
    if (tid < 64) g0s[tid] = decf(gmax[tid * 16]);
    __syncthreads();
    if (tid < 64) {
        float a = bg[tid];
        for (int c = 0; c < 64; ++c) a += g0s[c] * Wg[c * 64 + tid];
        g1s[tid] = fmaxf(a, 0.f);
    }
    __syncthreads();
    if (tid < 64) {
        float b = bn[tid];
        for (int c = 0; c < 64; ++c) b += g1s[c] * Wn[(64 + c) * 64 + tid];
        cvs[tid] = b;
    }
    __syncthreads();

    const int lane = tid & 63;
    const int cs = lane & 15;
    const int sub = lane >> 4;
    float4 wo4 = *(const float4*)(Wo + cs * 4);
    float woa[4] = {wo4.x, wo4.y, wo4.z, wo4.w};
    float cv0 = cvs[cs * 4 + 0], cv1 = cvs[cs * 4 + 1], cv2 = cvs[cs * 4 + 2], cv3 = cvs[cs * 4 + 3];
    float bo0 = bo[0];

#pragma unroll
    for (int nb = 0; nb < 4; ++nb) {
        const int node = blockIdx.x * 64 + nb * 16 + (tid >> 6) * 4 + sub;
        float4 h4 = *(const float4*)(h + (size_t)node * Cc + cs * 4);
        float hv[4] = {h4.x, h4.y, h4.z, h4.w};
        float inner[4] = {cv0, cv1, cv2, cv3};
#pragma unroll
        for (int c = 0; c < 64; ++c) {
            float hc = __shfl(hv[c & 3], sub * 16 + (c >> 2));
            float4 wv = *(const float4*)&wns[c * 64 + cs * 4];
            inner[0] = fmaf(hc, wv.x, inner[0]);
            inner[1] = fmaf(hc, wv.y, inner[1]);
            inner[2] = fmaf(hc, wv.z, inner[2]);
            inner[3] = fmaf(hc, wv.w, inner[3]);
        }
        float t = 0.f;
#pragma unroll
        for (int j = 0; j < 4; ++j) {
            float v = fmaxf(inner[j], 0.f);
            t = fmaf(v, woa[j], t);
        }
        t += __shfl_xor(t, 1); t += __shfl_xor(t, 2);
        t += __shfl_xor(t, 4); t += __shfl_xor(t, 8);
        if (cs == 0) out[node] = t + bo0;
    }
}

// ---------- launch ----------
extern "C" void kernel_launch(void* const* d_in, const int* in_sizes, int n_in,
                              void* d_out, int out_size, void* d_ws, size_t ws_size,
                              hipStream_t stream) {
    const float* x     = (const float*)d_in[0];
    const int*   ei    = (const int*)d_in[1];
    const float* ew    = (const float*)d_in[2];
    const float* Wl1   = (const float*)d_in[3];
    const float* bl1v  = (const float*)d_in[4];
    const float* Wr1   = (const float*)d_in[5];
    const float* br1v  = (const float*)d_in[6];
    const float* We1   = (const float*)d_in[7];
    const float* att1  = (const float*)d_in[8];
    const float* bias1 = (const float*)d_in[9];
    const float* Wl2   = (const float*)d_in[10];
    const float* bl2v  = (const float*)d_in[11];
    const float* Wr2   = (const float*)d_in[12];
    const float* br2v  = (const float*)d_in[13];
    const float* We2   = (const float*)d_in[14];
    const float* att2  = (const float*)d_in[15];
    const float* bias2 = (const float*)d_in[16];
    const float* Wg    = (const float*)d_in[17];
    const float* bgv   = (const float*)d_in[18];
    const float* Wn    = (const float*)d_in[19];
    const float* bnv   = (const float*)d_in[20];
    const float* Wo    = (const float*)d_in[21];
    const float* bov   = (const float*)d_in[22];
    float* out = (float*)d_out;

    char* w = (char*)d_ws;
    size_t o = 0;
    auto take = [&](size_t b) -> char* {
        char* p = w + o;
        o += (b + 255) & ~(size_t)255;
        return p;
    };
    unsigned short* xlr1 = (unsigned short*)take((size_t)GNP * 1024 * 2);     // 82 MB
    unsigned short* xb   = (unsigned short*)take((size_t)GNP * Ff * 2);       // 10.26 MB
    unsigned short* xlr2 = (unsigned short*)take((size_t)GNP * 128 * 2);      // 10.26 MB
    unsigned short* Wt1  = (unsigned short*)take(1024 * 128 * 2);
    unsigned short* Wt2  = (unsigned short*)take(128 * 512 * 2);
    float* b1cat = (float*)take(1024 * 4);
    float* b2cat = (float*)take(128 * 4);
    int*    cnt   = (int*)take((size_t)GN * 4);
    float*  loopw = (float*)take((size_t)GN * 4);
    int2*   sedge = (int2*)take((size_t)GN * DEGMAX * 8);                     // 15.36 MB
    unsigned* gmax = (unsigned*)take(1024 * 4);
    // overlays
    unsigned short* h1 = xlr1 + 512; // row stride 1024, aliases xr half
    float* hbuf = (float*)xb;        // xb dead after gemm1

    hipMemsetAsync(cnt, 0, (size_t)GN * 4, stream);

    castprep_k<<<((GNP * Ff / 4) + 255) / 256, 256, 0, stream>>>(
        x, xb, Wl1, Wr1, bl1v, br1v, Wl2, Wr2, bl2v, br2v, Wt1, Wt2, b1cat, b2cat,
        cnt, gmax, ei, ew, sedge);

    gemm1_k<<<dim3(GNP / 128, 8), 256, 0, stream>>>(xb, Wt1, b1cat, xlr1, GN);

    agg1_k<<<GN / 4, 256, 0, stream>>>(xlr1, sedge, cnt, att1, We1, bias1, h1, loopw);

    gemm2_k<<<GNP / 64, 128, 0, stream>>>(h1, 1024, Wt2, b2cat, xlr2, GN);

    agg2_k<<<GN / 16, 1024, 0, stream>>>(xlr2, sedge, cnt, loopw, att2, We2, bias2, hbuf, gmax);

    final_k<<<GN / 64, 256, 0, stream>>>(hbuf, gmax, Wg, bgv, Wn, bnv, Wo, bov, out);

    (void)in_sizes; (void)n_in; (void)out_size; (void)ws_size;
}